// Round 8
// baseline (71.266 us; speedup 1.0000x reference)
//
#include <hip/hip_runtime.h>

// TcEmbedding: x (B=4, S=4096, D=64) f32.
// norms[b,t] = sum_d |x[b,t,d]|
// tc[b,t]   = t - j, j = nearest index < t with norms[j] < 0.7*(norms[t]+1e-8), else 0.
//
// R8: ONE dispatch. R7 (two kernels) = 57.3us = 42.7us harness floor (ws
// re-poison fill + restore + graph) + ~14.6us of A+gap+B. Fuse via a cheap
// device barrier that avoids every prior failure mode:
//   R4 coop grid.sync: +45us (graph-serialized exclusive launch).
//   R5 per-lane ACQUIRE spins on 64 addrs x 4096 waves: 98us (each acquire
//      is cache maintenance on 8 non-coherent XCDs).
//   R8: per block: release fence + ONE atomicAdd; ONE poller/block (256
//      total) on ONE counter line, RELAXED agent loads + s_sleep; ONE
//      acquire fence; __syncthreads. Counter init = ws poison 0xAAAAAAAA
//      (re-poisoned before every launch — proven stable by R5), target =
//      poison + 256. 256 blocks x 1024thr = 1 block/CU (co-resident);
//      bounded spin + recompute-from-x fallback as insurance.
// f64 norms/compares: a compare flip near the 0.7 threshold changes tc by
// O(S) >> absmax tolerance (R1-R7: absmax 0).

#define SS 4096
typedef unsigned long long u64;
typedef unsigned int u32;

__global__ void __launch_bounds__(1024)
tc_fused_kernel(const float4* __restrict__ x4, double* __restrict__ nrm,
                double* __restrict__ cmn, u32* __restrict__ counter,
                float* __restrict__ out)
{
    __shared__ double snc[64];     // own chunk's norms
    __shared__ double smin[16];    // per-wave partial minima
    __shared__ double sall[SS];    // fallback-only: recomputed prefix norms
    __shared__ double scmf[64];    // fallback-only: recomputed chunk minima
    __shared__ int    sflag;

    int ci   = blockIdx.x;         // chunk id = b*64 + c
    int b    = ci >> 6;
    int c    = ci & 63;
    int wave = threadIdx.x >> 6;
    int lane = threadIdx.x & 63;
    int g    = lane >> 4;          // row within wave's 4
    int e    = lane & 15;          // float4 index within row

    // ---- Phase 1: own chunk's 64 norms, one float4 round (16 waves x 4) --
    {
        int rl  = (wave << 2) + g;
        int row = (ci << 6) + rl;
        float4 p = x4[row * 16 + e];
        double a = (double)fabsf(p.x) + (double)fabsf(p.y)
                 + (double)fabsf(p.z) + (double)fabsf(p.w);
        #pragma unroll
        for (int off = 8; off > 0; off >>= 1)     // reduce within 16-lane group
            a += __shfl_xor(a, off, 64);
        if (e == 0) { nrm[row] = a; snc[rl] = a; }
        double m = (e == 0) ? a : 1e300;
        double o = __shfl_xor(m, 16, 64); m = (o < m) ? o : m;
        o        = __shfl_xor(m, 32, 64); m = (o < m) ? o : m;
        if (lane == 0) smin[wave] = m;
    }
    __syncthreads();                               // also drains nrm stores
    if (threadIdx.x < 16) {
        double m2 = smin[threadIdx.x];
        #pragma unroll
        for (int off = 8; off > 0; off >>= 1) {
            double o = __shfl_xor(m2, off, 64);
            m2 = (o < m2) ? o : m2;
        }
        if (threadIdx.x == 0) cmn[ci] = m2;
    }

    // ---- Device barrier: release + arrive; single relaxed poller/block ---
    if (threadIdx.x == 0) {
        __threadfence();                           // publish nrm + cmn
        atomicAdd(counter, 1u);                    // device-scope (m20)
        const u32 target = 0xAAAAAAAAu + 256u;     // ws poison + grid size
        int spins = 0, to = 0;
        while (__hip_atomic_load(counter, __ATOMIC_RELAXED,
                                 __HIP_MEMORY_SCOPE_AGENT) != target) {
            if (++spins > 1500) { to = 1; break; } // ~0.7ms cap, never expected
            __builtin_amdgcn_s_sleep(8);
        }
        __threadfence();                           // acquire: invalidate caches
        sflag = to;
    }
    __syncthreads();
    bool timeout = (sflag != 0);

    // ---- Insurance only: recompute prefix from x (self-contained) --------
    if (timeout) {
        for (int ch = wave; ch < c; ch += 16) {
            double mn = 1e300;
            for (int rr = 0; rr < 16; ++rr) {
                int rl = (ch << 6) + (rr << 2) + g;
                float4 p = x4[((b << 12) + rl) * 16 + e];
                double a = (double)fabsf(p.x) + (double)fabsf(p.y)
                         + (double)fabsf(p.z) + (double)fabsf(p.w);
                #pragma unroll
                for (int off = 8; off > 0; off >>= 1)
                    a += __shfl_xor(a, off, 64);
                if (e == 0) sall[rl] = a;
                mn = (a < mn) ? a : mn;
            }
            #pragma unroll
            for (int off = 16; off < 64; off <<= 1) {
                double o = __shfl_xor(mn, off, 64);
                mn = (o < mn) ? o : mn;
            }
            if (lane == 0) scmf[ch] = mn;
        }
        __syncthreads();
    }

    // ---- Phase 2: two-level ballot search (R7-proven) --------------------
    double v  = snc[lane];
    double cm = timeout ? scmf[lane] : cmn[(b << 6) + lane]; // lane>=c gated
    float res[4];
    #pragma unroll
    for (int k = 0; k < 4; ++k) {
        int pos = (wave << 2) + k;                 // t = c*64 + pos
        double thr = 0.7 * (snc[pos] + 1e-8);
        int r = 0;
        // (a) partial current chunk: j in [c*64, t)
        u64 m = __ballot(lane < pos && v < thr);
        if (m) {                                   // wave-uniform
            r = pos - (63 - __clzll(m));
        } else {
            // (b) nearest earlier chunk whose min qualifies
            u64 mc = __ballot(lane < c && cm < thr);
            if (mc) {
                int cc = 63 - __clzll(mc);         // wave-uniform
                // (c) nearest element in that chunk (non-empty by cmin)
                double v2 = timeout ? sall[(cc << 6) + lane]
                                    : nrm[(b << 12) + (cc << 6) + lane];
                u64 m2 = __ballot(v2 < thr);
                r = ((c - cc) << 6) + pos - (63 - __clzll(m2));
            }
        }
        res[k] = (float)r;
    }
    if (lane == 0)
        ((float4*)out)[ci * 16 + wave] =
            make_float4(res[0], res[1], res[2], res[3]);
}

extern "C" void kernel_launch(void* const* d_in, const int* in_sizes, int n_in,
                              void* d_out, int out_size, void* d_ws, size_t ws_size,
                              hipStream_t stream) {
    const float4* x4 = (const float4*)d_in[0];
    float* out = (float*)d_out;
    int nrows  = in_sizes[0] / 64;      // B*S   = 16384
    int nchunk = nrows / 64;            // 256

    double* nrm = (double*)d_ws;                      // 128 KB
    double* cmn = nrm + nrows;                        // 2 KB
    u32* counter = (u32*)((char*)d_ws + (size_t)nrows * 8 + (size_t)nchunk * 8);
    // counter sits on its own poisoned cache line (offset 133120, 128B-aligned)

    tc_fused_kernel<<<nchunk, 1024, 0, stream>>>(x4, nrm, cmn, counter, out);
}

// Round 9
// 59.203 us; speedup vs baseline: 1.2038x; 1.2038x over previous
//
#include <hip/hip_runtime.h>

// TcEmbedding: x (B=4, S=4096, D=64) f32.
// norms[b,t] = sum_d |x[b,t,d]|
// tc[b,t]   = t - j, j = nearest index < t with norms[j] < 0.7*(norms[t]+1e-8), else 0.
//
// R9: proven two-dispatch structure (kernel boundary = the only cheap
// device-wide barrier on this 8-XCD part; R4 coop +45us, R5 acquire-spin
// +40us, R8 relaxed-counter barrier +14us — all intra-dispatch sync lost).
//  A: sync-free norms. 1024 blocks x 256 thr; wave = 4 rows, ONE float4
//     round + 16-lane f64 shuffle reduce + 8B store. No LDS, no barrier.
//  B: self-contained scan. 256 blocks x 1024 thr (block = one 64-t chunk):
//     stage the whole 4096-double norm row (2x16B rounds/lane), build all
//     64 chunk-minima in-block, then the two-level ballot search fully
//     LDS-resident (no dependent L2 load in the loop).
// f64 norms/compares: a compare flip near the 0.7 threshold changes tc by
// O(S) >> absmax tolerance; min/compare exact in f64 (R1-R8: absmax 0).

#define SS 4096
typedef unsigned long long u64;

// ---------------- Kernel A: norms only, sync-free --------------------------
__global__ void __launch_bounds__(256)
tc_norms_kernel(const float4* __restrict__ x4, double* __restrict__ nrm)
{
    int wave = threadIdx.x >> 6;
    int lane = threadIdx.x & 63;
    int g    = lane >> 4;               // row within wave's 4 (0..3)
    int e    = lane & 15;               // float4 index within row (0..15)

    int row = (blockIdx.x << 4) + (wave << 2) + g;   // 16 rows per block
    float4 p = x4[row * 16 + e];        // 64 lanes = 4 rows, 1KB coalesced
    double a = (double)fabsf(p.x) + (double)fabsf(p.y)
             + (double)fabsf(p.z) + (double)fabsf(p.w);
    #pragma unroll
    for (int off = 8; off > 0; off >>= 1)   // reduce within 16-lane group
        a += __shfl_xor(a, off, 64);
    if (e == 0) nrm[row] = a;               // 4 consecutive 8B stores coalesce
}

// ---------------- Kernel B: all-LDS two-level ballot search ----------------
__global__ void __launch_bounds__(1024)
tc_scan_kernel(const double* __restrict__ nrm, float* __restrict__ out)
{
    __shared__ double sn[SS];           // full norm row (32 KB)
    __shared__ double scm[64];          // chunk minima

    int ci   = blockIdx.x;              // b*64 + c
    int b    = ci >> 6;
    int c    = ci & 63;
    int wave = threadIdx.x >> 6;
    int lane = threadIdx.x & 63;

    // Stage the whole row: 1024 threads x 2 double2 = 4096 doubles.
    const double2* row2 = (const double2*)(nrm + ((size_t)b << 12));
    ((double2*)sn)[threadIdx.x]        = row2[threadIdx.x];
    ((double2*)sn)[threadIdx.x + 1024] = row2[threadIdx.x + 1024];
    __syncthreads();

    // Chunk minima: wave w -> chunks 4w..4w+3 (LDS reads, 8B stride = free).
    #pragma unroll
    for (int q = 0; q < 4; ++q) {
        int ch = (wave << 2) + q;
        double m = sn[(ch << 6) + lane];
        #pragma unroll
        for (int off = 32; off > 0; off >>= 1) {
            double o = __shfl_xor(m, off, 64);
            m = (o < m) ? o : m;
        }
        if (lane == 0) scm[ch] = m;
    }
    __syncthreads();

    // Two-level ballot search; wave w handles t = c*64 + 4w..4w+3.
    double v  = sn[(c << 6) + lane];    // own chunk's norms
    double cm = scm[lane];              // minima (lane>=c gated below)
    float res[4];
    #pragma unroll
    for (int k = 0; k < 4; ++k) {
        int pos = (wave << 2) + k;
        double thr = 0.7 * (sn[(c << 6) + pos] + 1e-8);
        int r = 0;
        // (a) partial current chunk: j in [c*64, t)
        u64 m = __ballot(lane < pos && v < thr);
        if (m) {                        // wave-uniform (scalar mask)
            r = pos - (63 - __clzll(m));
        } else {
            // (b) nearest earlier chunk whose min qualifies
            u64 mc = __ballot(lane < c && cm < thr);
            if (mc) {
                int cc = 63 - __clzll(mc);          // wave-uniform
                // (c) nearest element in that chunk (non-empty by its min)
                double v2 = sn[(cc << 6) + lane];   // LDS, no L2 dip
                u64 m2 = __ballot(v2 < thr);
                r = ((c - cc) << 6) + pos - (63 - __clzll(m2));
            }
        }
        res[k] = (float)r;
    }
    if (lane == 0)
        ((float4*)out)[ci * 16 + wave] =
            make_float4(res[0], res[1], res[2], res[3]);
}

extern "C" void kernel_launch(void* const* d_in, const int* in_sizes, int n_in,
                              void* d_out, int out_size, void* d_ws, size_t ws_size,
                              hipStream_t stream) {
    const float4* x4 = (const float4*)d_in[0];
    float* out = (float*)d_out;
    int nrows  = in_sizes[0] / 64;      // B*S   = 16384
    int nchunk = nrows / 64;            // 256

    double* nrm = (double*)d_ws;        // 128 KB workspace

    tc_norms_kernel<<<nrows / 16, 256, 0, stream>>>(x4, nrm);
    tc_scan_kernel<<<nchunk, 1024, 0, stream>>>(nrm, out);
}

// Round 10
// 57.029 us; speedup vs baseline: 1.2496x; 1.0381x over previous
//
#include <hip/hip_runtime.h>

// TcEmbedding: x (B=4, S=4096, D=64) f32.
// norms[b,t] = sum_d |x[b,t,d]|
// tc[b,t]   = t - j, j = nearest index < t with norms[j] < 0.7*(norms[t]+1e-8), else 0.
//
// FINAL (revert to R7, best measured = 57.3us):
// Two dispatches; the kernel boundary is the only cheap device-wide barrier
// on this 8-XCD part. Ledger of alternatives, all measured worse:
//   R4 cooperative grid.sync      : +45us (graph-serialized exclusive launch)
//   R5 per-lane acquire spin      : +40us (acquire = cache maint. x8 XCDs)
//   R8 relaxed atomic counter bar : +14us (counter line ping-pong on fabric)
//   R6 sync-free full recompute   : kernel 43us (worst block reads 1MB via
//                                   one CU's L2 port + crossbar reduces)
//   R9 self-contained B           : +1.9us (32KB restage > rare L2 dip)
// Breakdown at 57.3us: ~41us harness ws-poison fill (268MB, fixed) + ~2us
// restore/out-poison + ~14us A+gap+B (mostly graph-node launch latency).
//  A: block = chunk (256 x 1024): wave w -> rows 4w..4w+3 in ONE float4
//     round, f64 16-lane shuffle reduce, block min via 16-entry LDS -> cmin.
//  B: block = chunk: stage own 64 norms + 64 chunk-minima (1KB LDS), 16
//     waves x 4 t two-level ballot search; step-(c) chunk read from L2.
// f64 norms/compares throughout: a compare flip near the 0.7 threshold
// changes tc by O(S) >> absmax tolerance (R1-R9: absmax 0 every round).

#define SS 4096
typedef unsigned long long u64;

// ---------------- Kernel A: norms + chunk minima, one round per wave -------
template <typename T>
__global__ void __launch_bounds__(1024)
tc_norms_kernel(const float4* __restrict__ x4, T* __restrict__ nrm,
                T* __restrict__ cmn)
{
    __shared__ T smin[16];
    int ci   = blockIdx.x;              // chunk id = b*64 + c
    int wave = threadIdx.x >> 6;
    int lane = threadIdx.x & 63;
    int g    = lane >> 4;               // row within wave's 4 (0..3)
    int e    = lane & 15;               // float4 index within row

    int row = (ci << 6) + (wave << 2) + g;
    float4 p = x4[row * 16 + e];        // 64 lanes = 4 rows, 1KB coalesced
    T a = (T)fabsf(p.x) + (T)fabsf(p.y) + (T)fabsf(p.z) + (T)fabsf(p.w);
    #pragma unroll
    for (int off = 8; off > 0; off >>= 1)   // reduce within 16-lane group
        a += __shfl_xor(a, off, 64);
    if (e == 0) nrm[row] = a;               // lane e==0 holds the row norm

    // wave min over its 4 rows (valid only at e==0 lanes; mask others)
    T m = (e == 0) ? a : (T)1e300;
    {
        T o = __shfl_xor(m, 16, 64); m = (o < m) ? o : m;
        o   = __shfl_xor(m, 32, 64); m = (o < m) ? o : m;
    }
    if (lane == 0) smin[wave] = m;
    __syncthreads();
    if (threadIdx.x < 16) {                 // wave 0: min across 16 waves
        T m2 = smin[threadIdx.x];
        #pragma unroll
        for (int off = 8; off > 0; off >>= 1) {
            T o = __shfl_xor(m2, off, 64);
            m2 = (o < m2) ? o : m2;
        }
        if (threadIdx.x == 0) cmn[ci] = m2;
    }
}

// ---------------- Kernel B: two-level ballot search, LDS-staged ------------
template <typename T>
__global__ void __launch_bounds__(1024)
tc_scan_kernel(const T* __restrict__ nrm, const T* __restrict__ cmn,
               float* __restrict__ out)
{
    __shared__ T sn[64];                // own chunk's norms
    __shared__ T scm[64];               // row's 64 chunk minima
    int ci   = blockIdx.x;              // b*64 + c
    int b    = ci >> 6;
    int c    = ci & 63;
    int wave = threadIdx.x >> 6;
    int lane = threadIdx.x & 63;

    if (wave == 0)      sn[lane]  = nrm[(ci << 6) + lane];
    else if (wave == 1) scm[lane] = cmn[(b << 6) + lane];
    __syncthreads();

    T v  = sn[lane];
    T cm = scm[lane];
    float res[4];
    #pragma unroll
    for (int k = 0; k < 4; ++k) {
        int pos = (wave << 2) + k;      // t = c*64 + pos
        T thr = (T)0.7 * (sn[pos] + (T)1e-8);
        int r = 0;
        // (a) partial current chunk: j in [c*64, t)
        u64 m = __ballot(lane < pos && v < thr);
        if (m) {                        // wave-uniform (m is scalar)
            r = pos - (63 - __clzll(m));
        } else {
            // (b) nearest earlier chunk whose min qualifies
            u64 mc = __ballot(lane < c && cm < thr);
            if (mc) {
                int cc = 63 - __clzll(mc);                 // wave-uniform
                // (c) nearest element in that chunk (non-empty by cmin), L2
                T v2 = nrm[(b << 12) + (cc << 6) + lane];
                u64 m2 = __ballot(v2 < thr);
                r = ((c - cc) << 6) + pos - (63 - __clzll(m2));
            }
        }
        res[k] = (float)r;
    }
    if (lane == 0)
        ((float4*)out)[ci * 16 + wave] =
            make_float4(res[0], res[1], res[2], res[3]);
}

extern "C" void kernel_launch(void* const* d_in, const int* in_sizes, int n_in,
                              void* d_out, int out_size, void* d_ws, size_t ws_size,
                              hipStream_t stream) {
    const float4* x4 = (const float4*)d_in[0];
    float* out = (float*)d_out;
    int nrows  = in_sizes[0] / 64;      // B*S   = 16384
    int nchunk = nrows / 64;            // 256

    if (ws_size >= (size_t)(nrows + nchunk) * sizeof(double)) {
        double* nrm = (double*)d_ws;
        double* cmn = nrm + nrows;
        tc_norms_kernel<double><<<nchunk, 1024, 0, stream>>>(x4, nrm, cmn);
        tc_scan_kernel<double><<<nchunk, 1024, 0, stream>>>(nrm, cmn, out);
    } else {
        float* nrm = (float*)d_ws;
        float* cmn = nrm + nrows;
        tc_norms_kernel<float><<<nchunk, 1024, 0, stream>>>(x4, nrm, cmn);
        tc_scan_kernel<float><<<nchunk, 1024, 0, stream>>>(nrm, cmn, out);
    }
}